// Round 21
// baseline (233.449 us; speedup 1.0000x reference)
//
#include <hip/hip_runtime.h>

// Problem constants
constexpr int B    = 32;
constexpr int CIN  = 64;
constexpr int COUT = 128;
constexpr int T    = 300;
constexpr int V    = 25;
constexpr int TV   = T * V;            // 7500
constexpr long long NPC   = (long long)B * TV;          // 240000 per channel
constexpr long long TOTAL = (long long)B * COUT * TV;   // 30,720,000

typedef short          bf16x8 __attribute__((ext_vector_type(8)));
typedef float          f32x4  __attribute__((ext_vector_type(4)));
typedef unsigned short us8    __attribute__((ext_vector_type(8)));
typedef unsigned short us4    __attribute__((ext_vector_type(4)));

static __device__ __forceinline__ unsigned short f2bf(float f) {
  union { float f; unsigned u; } x; x.f = f;
  unsigned r = x.u + 0x7FFFu + ((x.u >> 16) & 1u);   // RNE
  return (unsigned short)(r >> 16);
}
static __device__ __forceinline__ float bf2f(unsigned short u) {
  union { unsigned u; float f; } x; x.u = ((unsigned)u) << 16;
  return x.f;
}
// HW packed f32->bf16 (RNE): dst = [lo16=cvt(a), hi16=cvt(b)]
static __device__ __forceinline__ unsigned cvtpk(float a, float b) {
  unsigned r;
  asm("v_cvt_pk_bf16_f32 %0, %1, %2" : "=v"(r) : "v"(a), "v"(b));
  return r;
}

// swizzled offsets (verified rounds 4-20)
static __device__ __forceinline__ int xoff(int pos, int c) {      // [pos][c<64]
  return pos * 64 + ((((c >> 3)) ^ (pos & 7)) << 3) + (c & 7);
}
static __device__ __forceinline__ int soff(int c, int pw) {       // [c][pw<128]
  return c * 128 + ((((pw >> 3)) ^ (c & 7)) << 3) + (pw & 7);
}

// ---------------------------------------------------------------------------
// kPrep: all weight/graph-matrix prep in one launch. 696 blocks x 256.
// ---------------------------------------------------------------------------
__global__ __launch_bounds__(256) void kPrep(
    const float* __restrict__ w_t, const float* __restrict__ w_r,
    const float* __restrict__ w_sp, const float* __restrict__ A_hat,
    unsigned short* __restrict__ wb2, unsigned short* __restrict__ wrs2,
    unsigned short* __restrict__ bdt)
{
  int i = blockIdx.x * 256 + threadIdx.x;
  if (i < 147456) {
    int c = i & 127, ok = i >> 7;
    int k = ok % 9, o = ok / 9;
    int idx = ((k * 16 + (c >> 3)) * 128 + o) * 8 + (c & 7);
    wb2[idx] = f2bf(w_t[(o * COUT + c) * 9 + k]);
  } else if (i < 147456 + 16384) {
    int j = i - 147456;
    int c = j & 63, row = j >> 6;
    float v = (row < COUT) ? w_r[row * CIN + c] : w_sp[(row - COUT) * CIN + c];
    wrs2[((c >> 3) * 256 + row) * 8 + (c & 7)] = f2bf(v);
  } else {
    int j = i - 147456 - 16384;
    int pv = j >> 7, pw = j & 127;
    float v = 0.f;
    if (pv < 100 && pw < 100 && (pv / 25) == (pw / 25))
      v = A_hat[(pv % 25) * 25 + (pw % 25)];
    bdt[j] = f2bf(v);
  }
}

// ---------------------------------------------------------------------------
// kA9: spatial front-end, BOTH paths sequentially in one block (x staged
// once per tile; second layout pass is L1/L2-hot). 256 thr / 4 waves,
// acc[2][7] reused across phases (~60 VGPR), LDS 30KB -> 5 blocks/CU.
// Phases: stage(xs + xsp) | S1 | res GEMM+epi+stats | xf load | S2 |
// mix -> axsp(=xs) | S3 | sp GEMM+epi+stats. grid (75, 32).
// ---------------------------------------------------------------------------
__global__ __launch_bounds__(256, 3) void kA9(
    const float* __restrict__ x, const unsigned short* __restrict__ bdt,
    const unsigned short* __restrict__ wrs2,
    unsigned short* __restrict__ resb, unsigned short* __restrict__ h,
    float2* __restrict__ part_rs)
{
  __shared__ unsigned short xs[64 * 128];    // 16KB [c][pw]; becomes axsp
  __shared__ unsigned short xsp[112 * 64];   // 14KB [pos][c]

  const int tid  = threadIdx.x;
  const int lane = tid & 63;
  const int wave = tid >> 6;
  const int b    = blockIdx.y;
  const int p0   = blockIdx.x * 100;
  const int grp  = lane >> 4;
  const int l15  = lane & 15;
  const long long bid2 = ((long long)(blockIdx.y * 75 + blockIdx.x)) * 2;

  // ---- stage xs [c][pw]: float4 along pos + us4 pack (r20-proven)
  for (int u = tid; u < 64 * 32; u += 256) {
    int q = u & 31, c = u >> 5;
    int pos = q * 4;
    float4 v = make_float4(0.f, 0.f, 0.f, 0.f);
    if (pos < 100)
      v = *(const float4*)&x[(b * CIN + c) * TV + p0 + pos];
    us4 pk;
    unsigned u01 = cvtpk(v.x, v.y), u23 = cvtpk(v.z, v.w);
    pk[0] = (unsigned short)u01;
    pk[1] = (unsigned short)(u01 >> 16);
    pk[2] = (unsigned short)u23;
    pk[3] = (unsigned short)(u23 >> 16);
    *(us4*)&xs[soff(c, pos)] = pk;
  }
  // ---- stage xsp [pos][c]: scalar loads (L1/L2-hot; r16 z=0-proven)
  for (int u = tid; u < 16 * 112; u += 256) {
    int pos = u % 112, c4 = u / 112;
    int c0 = c4 * 4;
    float v0 = 0.f, v1 = 0.f, v2 = 0.f, v3 = 0.f;
    if (pos < 100) {
      const float* xp = &x[(b * CIN + c0) * TV + p0 + pos];
      v0 = xp[0]; v1 = xp[TV]; v2 = xp[2 * TV]; v3 = xp[3 * TV];
    }
    uint2 w;
    w.x = cvtpk(v0, v1);
    w.y = cvtpk(v2, v3);
    *(uint2*)&xsp[xoff(pos, c0)] = w;
  }
  __syncthreads();                       // S1: both layouts staged

  f32x4 acc[2][7];
#pragma unroll
  for (int m = 0; m < 2; ++m)
#pragma unroll
    for (int n = 0; n < 7; ++n) acc[m][n] = (f32x4)0.f;

  // ---- res phase: channel GEMM from xsp (rows 0-127)
#pragma unroll
  for (int ks = 0; ks < 2; ++ks) {
    bf16x8 af[2], bfr[7];
#pragma unroll
    for (int mi = 0; mi < 2; ++mi) {
      int row = wave * 32 + mi * 16 + l15;
      af[mi] = *(const bf16x8*)&wrs2[((ks * 4 + grp) * 256 + row) * 8];
    }
#pragma unroll
    for (int ni = 0; ni < 7; ++ni)
      bfr[ni] = *(const bf16x8*)&xsp[xoff(ni * 16 + l15, ks * 32 + grp * 8)];
#pragma unroll
    for (int mi = 0; mi < 2; ++mi)
#pragma unroll
      for (int ni = 0; ni < 7; ++ni)
        acc[mi][ni] = __builtin_amdgcn_mfma_f32_16x16x32_bf16(
            af[mi], bfr[ni], acc[mi][ni], 0, 0, 0);
  }
  // res epilogue: resb scalar [b][c][pos]
#pragma unroll
  for (int mi = 0; mi < 2; ++mi) {
#pragma unroll
    for (int ni = 0; ni < 7; ++ni) {
      int pos = ni * 16 + l15;
      if (pos < 100) {
#pragma unroll
        for (int r = 0; r < 4; ++r) {
          int c = wave * 32 + mi * 16 + grp * 4 + r;
          resb[((long long)(b * COUT + c)) * TV + p0 + pos] = f2bf(acc[mi][ni][r]);
        }
      }
    }
  }
  // res stats (8-quantity butterfly)
  {
    float sv[8], qv[8];
#pragma unroll
    for (int mi = 0; mi < 2; ++mi)
#pragma unroll
      for (int r = 0; r < 4; ++r) {
        float s = 0.f, q = 0.f;
#pragma unroll
        for (int ni = 0; ni < 7; ++ni) {
          float v = (ni < 6 || l15 < 4) ? acc[mi][ni][r] : 0.f;  // pos<100
          s += v; q += v * v;
        }
        sv[mi * 4 + r] = s; qv[mi * 4 + r] = q;
      }
#pragma unroll
    for (int bm = 1; bm < 8; bm <<= 1) {
      const bool up = (l15 & bm) != 0;
#pragma unroll
      for (int i = 0; i < 8; i += 2 * bm) {
        const int j = i + bm;
        float ssend = up ? sv[i] : sv[j];
        float qsend = up ? qv[i] : qv[j];
        float sgot = __shfl_xor(ssend, bm);
        float qgot = __shfl_xor(qsend, bm);
        sv[i] = (up ? sv[j] : sv[i]) + sgot;
        qv[i] = (up ? qv[j] : qv[i]) + qgot;
      }
    }
    sv[0] += __shfl_xor(sv[0], 8);
    qv[0] += __shfl_xor(qv[0], 8);
    if ((l15 & 8) == 0) {
      int slot = ((l15 >> 2) * 16) + grp * 4 + (l15 & 3);
      part_rs[((bid2 + 0) * 4 + wave) * 32 + slot] = make_float2(sv[0], qv[0]);
    }
  }

  // ---- xf load (xs still valid), then release xs for axsp
  bf16x8 xf[4];
#pragma unroll
  for (int ks = 0; ks < 4; ++ks)
    xf[ks] = *(const bf16x8*)&xs[soff(wave * 16 + l15, ks * 32 + grp * 8)];
  __syncthreads();                       // S2: xs free

  // ---- mix GEMM (sparse block-diagonal k-steps, table VERIFIED round 5)
  {
    f32x4 macc[7];
#pragma unroll
    for (int ni = 0; ni < 7; ++ni) macc[ni] = (f32x4)0.f;
    const int kst[7] = {0, 0, 0, 0, 1, 2, 2};
    const int kcn[7] = {1, 2, 2, 3, 3, 2, 2};
#pragma unroll
    for (int ni = 0; ni < 7; ++ni) {
      for (int kk = 0; kk < kcn[ni]; ++kk) {
        int ks = kst[ni] + kk;
        bf16x8 gf = *(const bf16x8*)&bdt[(ni * 16 + l15) * 128 + ks * 32 + grp * 8];
        macc[ni] = __builtin_amdgcn_mfma_f32_16x16x32_bf16(xf[ks], gf, macc[ni], 0, 0, 0);
      }
    }
    unsigned short* axsp = (unsigned short*)xs;
#pragma unroll
    for (int ni = 0; ni < 7; ++ni) {
#pragma unroll
      for (int r = 0; r < 4; ++r)
        axsp[xoff(ni * 16 + l15, wave * 16 + grp * 4 + r)] = f2bf(macc[ni][r]);
    }
  }
  __syncthreads();                       // S3: axsp ready

  // ---- sp phase: channel GEMM from axsp (rows 128-255)
#pragma unroll
  for (int m = 0; m < 2; ++m)
#pragma unroll
    for (int n = 0; n < 7; ++n) acc[m][n] = (f32x4)0.f;

  const unsigned short* axsp = xs;
#pragma unroll
  for (int ks = 0; ks < 2; ++ks) {
    bf16x8 af[2], bfr[7];
#pragma unroll
    for (int mi = 0; mi < 2; ++mi) {
      int row = 128 + wave * 32 + mi * 16 + l15;
      af[mi] = *(const bf16x8*)&wrs2[((ks * 4 + grp) * 256 + row) * 8];
    }
#pragma unroll
    for (int ni = 0; ni < 7; ++ni)
      bfr[ni] = *(const bf16x8*)&axsp[xoff(ni * 16 + l15, ks * 32 + grp * 8)];
#pragma unroll
    for (int mi = 0; mi < 2; ++mi)
#pragma unroll
      for (int ni = 0; ni < 7; ++ni)
        acc[mi][ni] = __builtin_amdgcn_mfma_f32_16x16x32_bf16(
            af[mi], bfr[ni], acc[mi][ni], 0, 0, 0);
  }
  // sp epilogue: h uint2 [b][pos][c]
#pragma unroll
  for (int mi = 0; mi < 2; ++mi) {
    int o0 = wave * 32 + mi * 16 + grp * 4;
#pragma unroll
    for (int ni = 0; ni < 7; ++ni) {
      int pos = ni * 16 + l15;
      if (pos < 100) {
        uint2 w;
        w.x = cvtpk(acc[mi][ni][0], acc[mi][ni][1]);
        w.y = cvtpk(acc[mi][ni][2], acc[mi][ni][3]);
        *(uint2*)&h[((long long)(b * TV + p0 + pos)) * COUT + o0] = w;
      }
    }
  }
  // sp stats
  {
    float sv[8], qv[8];
#pragma unroll
    for (int mi = 0; mi < 2; ++mi)
#pragma unroll
      for (int r = 0; r < 4; ++r) {
        float s = 0.f, q = 0.f;
#pragma unroll
        for (int ni = 0; ni < 7; ++ni) {
          float v = (ni < 6 || l15 < 4) ? acc[mi][ni][r] : 0.f;  // pos<100
          s += v; q += v * v;
        }
        sv[mi * 4 + r] = s; qv[mi * 4 + r] = q;
      }
#pragma unroll
    for (int bm = 1; bm < 8; bm <<= 1) {
      const bool up = (l15 & bm) != 0;
#pragma unroll
      for (int i = 0; i < 8; i += 2 * bm) {
        const int j = i + bm;
        float ssend = up ? sv[i] : sv[j];
        float qsend = up ? qv[i] : qv[j];
        float sgot = __shfl_xor(ssend, bm);
        float qgot = __shfl_xor(qsend, bm);
        sv[i] = (up ? sv[j] : sv[i]) + sgot;
        qv[i] = (up ? qv[j] : qv[i]) + qgot;
      }
    }
    sv[0] += __shfl_xor(sv[0], 8);
    qv[0] += __shfl_xor(qv[0], 8);
    if ((l15 & 8) == 0) {
      int slot = ((l15 >> 2) * 16) + grp * 4 + (l15 & 3);
      part_rs[((bid2 + 1) * 4 + wave) * 32 + slot] = make_float2(sv[0], qv[0]);
    }
  }
}

// ---------------------------------------------------------------------------
// kC2v2: finalize res & sp BN from kA9 partials. grid 256. (layout unchanged)
// ---------------------------------------------------------------------------
__global__ __launch_bounds__(256) void kC2v2(
    const float2* __restrict__ part_rs,
    const float* __restrict__ g_r,  const float* __restrict__ be_r,
    const float* __restrict__ g_sp, const float* __restrict__ be_sp,
    float* __restrict__ scales)
{
  __shared__ float rs[256], rq[256];
  const int row = blockIdx.x;
  const int z = row >> 7, wave = (row >> 5) & 3, slot = row & 31;
  const int tid = threadIdx.x;
  float s = 0.f, q = 0.f;
  for (int bid = tid; bid < 2400; bid += 256) {
    float2 v = part_rs[(((long long)bid * 2 + z) * 4 + wave) * 32 + slot];
    s += v.x; q += v.y;
  }
  rs[tid] = s; rq[tid] = q;
  __syncthreads();
  for (int st = 128; st > 0; st >>= 1) {
    if (tid < st) { rs[tid] += rs[tid + st]; rq[tid] += rq[tid + st]; }
    __syncthreads();
  }
  if (tid == 0) {
    const float n = (float)NPC;
    float m = rs[0] / n, var = rq[0] / n - m * m;
    float iv = rsqrtf(var + 1e-5f);
    if (row < 128) {
      float sc = g_r[row] * iv;
      scales[row] = sc; scales[128 + row] = be_r[row] - m * sc;
    } else {
      int c = row - 128;
      float sc = g_sp[c] * iv;
      scales[256 + c] = sc; scales[384 + c] = be_sp[c] - m * sc;
    }
  }
}

// ---------------------------------------------------------------------------
// kE7d: temporal conv 9x1, implicit MFMA GEMM. NP=256, 512 threads / 8
// waves, single 58KB LDS (r15/r16/r20-proven form). cvb scalar [b][c][pos];
// butterfly BN_t stats; setprio. grid (30, 32).
// ---------------------------------------------------------------------------
constexpr int NP    = 256;
constexpr int HALO  = 100;               // 4*25
constexpr int STAGE = NP + 2 * HALO;     // 456

__global__ __launch_bounds__(512, 2) void kE7d(
    const unsigned short* __restrict__ h, const unsigned short* __restrict__ wb2,
    const float* __restrict__ scales, unsigned short* __restrict__ cvb,
    float2* __restrict__ part_t)
{
  __shared__ unsigned short hs[STAGE * 64];   // 58368 B
  const int tid  = threadIdx.x;
  const int lane = tid & 63;
  const int wave = tid >> 6;          // 0..7
  const int wm   = wave >> 2, wn = wave & 3;
  const int b    = blockIdx.y;
  const int p0   = blockIdx.x * NP;
  const int grp  = lane >> 4;
  const int l15  = lane & 15;
  const int slot = tid & 7;

  f32x4 acc[4][4];
#pragma unroll
  for (int m = 0; m < 4; ++m)
#pragma unroll
    for (int n = 0; n < 4; ++n) acc[m][n] = (f32x4)0.f;

  for (int cc = 0; cc < 2; ++cc) {
    if (cc) __syncthreads();             // prev chunk's MFMA reads done
    const int c0 = cc * 64;
    float sc[8], sh[8];
#pragma unroll
    for (int e = 0; e < 8; ++e) {
      sc[e] = scales[256 + c0 + slot * 8 + e];
      sh[e] = scales[384 + c0 + slot * 8 + e];
    }
    for (int i = tid; i < STAGE * 8; i += 512) {
      int pos = i >> 3;
      int pg = p0 - HALO + pos;
      uint4 w = {0u, 0u, 0u, 0u};
      if (pg >= 0 && pg < TV) {
        us8 v = *(const us8*)&h[((long long)b * TV + pg) * COUT + c0 + slot * 8];
        float f[8];
#pragma unroll
        for (int e = 0; e < 8; ++e)
          f[e] = fmaxf(bf2f(v[e]) * sc[e] + sh[e], 0.f);
        w.x = cvtpk(f[0], f[1]);
        w.y = cvtpk(f[2], f[3]);
        w.z = cvtpk(f[4], f[5]);
        w.w = cvtpk(f[6], f[7]);
      }
      int si = (pos << 6) + ((slot ^ (pos & 7)) << 3);
      *(uint4*)&hs[si] = w;
    }
    __syncthreads();

    __builtin_amdgcn_s_setprio(1);
    for (int k = 0; k < 9; ++k) {
      const int plb = HALO + wn * 64 + 25 * (k - 4) + l15;
#pragma unroll
      for (int ks = 0; ks < 2; ++ks) {
        bf16x8 af[4], bfr[4];
#pragma unroll
        for (int mi = 0; mi < 4; ++mi) {
          int o = wm * 64 + mi * 16 + l15;
          af[mi] = *(const bf16x8*)&wb2[((k * 16 + cc * 8 + ks * 4 + grp) * 128 + o) * 8];
        }
#pragma unroll
        for (int ni = 0; ni < 4; ++ni) {
          int pl = plb + ni * 16;
          int si = (pl << 6) + (((ks * 4 + grp) ^ (pl & 7)) << 3);
          bfr[ni] = *(const bf16x8*)&hs[si];
        }
#pragma unroll
        for (int mi = 0; mi < 4; ++mi)
#pragma unroll
          for (int ni = 0; ni < 4; ++ni)
            acc[mi][ni] = __builtin_amdgcn_mfma_f32_16x16x32_bf16(
                af[mi], bfr[ni], acc[mi][ni], 0, 0, 0);
      }
    }
    __builtin_amdgcn_s_setprio(0);
  }

  // epilogue: conv -> cvb bf16, [b][c][pos] scalar (plane layout for kH)
#pragma unroll
  for (int mi = 0; mi < 4; ++mi) {
#pragma unroll
    for (int ni = 0; ni < 4; ++ni) {
      int pos = p0 + wn * 64 + ni * 16 + l15;
      if (pos < TV) {
#pragma unroll
        for (int r = 0; r < 4; ++r) {
          int o = wm * 64 + mi * 16 + grp * 4 + r;
          cvb[((long long)(b * COUT + o)) * TV + pos] = f2bf(acc[mi][ni][r]);
        }
      }
    }
  }

  // fused BN_t stats: transpose-butterfly, [bid][wave(8)][64]
  {
    float sv[16], qv[16];
#pragma unroll
    for (int mi = 0; mi < 4; ++mi)
#pragma unroll
      for (int r = 0; r < 4; ++r) {
        float s = 0.f, q = 0.f;
#pragma unroll
        for (int ni = 0; ni < 4; ++ni) {
          int pos = p0 + wn * 64 + ni * 16 + l15;
          float v = (pos < TV) ? acc[mi][ni][r] : 0.f;
          s += v; q += v * v;
        }
        sv[mi * 4 + r] = s; qv[mi * 4 + r] = q;
      }
#pragma unroll
    for (int bm = 1; bm < 16; bm <<= 1) {
      const bool up = (l15 & bm) != 0;
#pragma unroll
      for (int i = 0; i < 16; i += 2 * bm) {
        const int j = i + bm;
        float ssend = up ? sv[i] : sv[j];
        float qsend = up ? qv[i] : qv[j];
        float sgot = __shfl_xor(ssend, bm);
        float qgot = __shfl_xor(qsend, bm);
        sv[i] = (up ? sv[j] : sv[i]) + sgot;
        qv[i] = (up ? qv[j] : qv[i]) + qgot;
      }
    }
    int slt = ((l15 >> 2) * 16) + grp * 4 + (l15 & 3);
    float2* pw = &part_t[(((long long)(blockIdx.y * 30 + blockIdx.x)) * 8 + wave) * 64];
    pw[slt] = make_float2(sv[0], qv[0]);
  }
}

// ---------------------------------------------------------------------------
// kG2: finalize temporal BN from kE7d partials. grid 128. NB=960 blocks.
// ---------------------------------------------------------------------------
__global__ __launch_bounds__(256) void kG2(
    const float2* __restrict__ part_t,
    const float* __restrict__ g_t, const float* __restrict__ be_t,
    float* __restrict__ scales)
{
  __shared__ float rs[256], rq[256];
  const int c = blockIdx.x;
  const int wm = c >> 6, local = c & 63;
  const int tid = threadIdx.x;
  const int NB = 30 * 32;              // 960 blocks
  float s = 0.f, q = 0.f;
  for (int p = tid; p < NB * 4; p += 256) {
    int bid = p >> 2, wn = p & 3;
    float2 v = part_t[((long long)bid * 8 + (wm * 4 + wn)) * 64 + local];
    s += v.x; q += v.y;
  }
  rs[tid] = s; rq[tid] = q;
  __syncthreads();
  for (int st = 128; st > 0; st >>= 1) {
    if (tid < st) { rs[tid] += rs[tid + st]; rq[tid] += rq[tid + st]; }
    __syncthreads();
  }
  if (tid == 0) {
    const float n = (float)NPC;
    float m = rs[0] / n, var = rq[0] / n - m * m;
    float sc = g_t[c] * rsqrtf(var + 1e-5f);
    scales[512 + c] = sc;
    scales[640 + c] = be_t[c] - m * sc;
  }
}

// ---------------------------------------------------------------------------
// kH: out = relu(cvb*sc_t+sh_t + resb*sc_r+sh_r). Plane-based (proven).
// ---------------------------------------------------------------------------
__global__ __launch_bounds__(256) void kH(
    const unsigned short* __restrict__ cvb, const unsigned short* __restrict__ resb,
    const float* __restrict__ scales, float* __restrict__ out)
{
  const int plane = blockIdx.x;          // b*128 + c
  const int c = plane & 127;
  const float sct = scales[512 + c], sht = scales[640 + c];
  const float scr = scales[c],       shr = scales[128 + c];
  const us4* cp = (const us4*)&cvb[(long long)plane * TV];
  const us4* rp = (const us4*)&resb[(long long)plane * TV];
  float* op = &out[(long long)plane * TV];
  for (int u = threadIdx.x; u < 1875; u += 256) {
    us4 o4 = cp[u], r4 = rp[u];
    float4 y;
    y.x = fmaxf(bf2f(o4[0]) * sct + sht + bf2f(r4[0]) * scr + shr, 0.f);
    y.y = fmaxf(bf2f(o4[1]) * sct + sht + bf2f(r4[1]) * scr + shr, 0.f);
    y.z = fmaxf(bf2f(o4[2]) * sct + sht + bf2f(r4[2]) * scr + shr, 0.f);
    y.w = fmaxf(bf2f(o4[3]) * sct + sht + bf2f(r4[3]) * scr + shr, 0.f);
    *(float4*)&op[u * 4] = y;
  }
}

// ---------------------------------------------------------------------------
extern "C" void kernel_launch(void* const* d_in, const int* in_sizes, int n_in,
                              void* d_out, int out_size, void* d_ws, size_t ws_size,
                              hipStream_t stream) {
  const float* x     = (const float*)d_in[0];
  const float* A_hat = (const float*)d_in[1];
  const float* w_sp  = (const float*)d_in[2];
  const float* g_sp  = (const float*)d_in[4];
  const float* be_sp = (const float*)d_in[5];
  const float* w_t   = (const float*)d_in[6];
  const float* g_t   = (const float*)d_in[8];
  const float* be_t  = (const float*)d_in[9];
  const float* w_r   = (const float*)d_in[10];
  const float* g_r   = (const float*)d_in[12];
  const float* be_r  = (const float*)d_in[13];
  float* out = (float*)d_out;

  // workspace carving (shorts)
  unsigned short* base_us = (unsigned short*)d_ws;
  unsigned short* resb = base_us;                          // TOTAL ([b][c][pos])
  unsigned short* h    = base_us + (size_t)TOTAL;          // TOTAL ([b][pos][c])
  unsigned short* cvb  = base_us + (size_t)(2 * TOTAL);    // TOTAL ([b][c][pos])
  unsigned short* wb2  = base_us + (size_t)(3 * TOTAL);    // 147456
  unsigned short* wrs2 = wb2 + 147456;                     // 16384
  unsigned short* bdt  = wrs2 + 16384;                     // 14336
  float2* part_rs = (float2*)(bdt + 14336);                // 2400*2*4*32
  float2* part_t  = part_rs + 2400 * 2 * 4 * 32;           // 960*8*64
  float*  scales  = (float*)(part_t + 960 * 8 * 64);       // 768 floats

  // all prep in one launch
  kPrep<<<696, 256, 0, stream>>>(w_t, w_r, w_sp, A_hat, wb2, wrs2, bdt);
  // spatial front-end (merged paths, single staging, stats fused)
  kA9<<<dim3(75, 32), 256, 0, stream>>>(x, bdt, wrs2, resb, h, part_rs);
  kC2v2<<<256, 256, 0, stream>>>(part_rs, g_r, be_r, g_sp, be_sp, scales);
  // temporal conv (NP=256, cvt_pk staging, stats fused)
  kE7d<<<dim3(30, 32), 512, 0, stream>>>(h, wb2, scales, cvb, part_t);
  kG2<<<128, 256, 0, stream>>>(part_t, g_t, be_t, scales);
  // fused epilogue (plane-based)
  kH<<<4096, 256, 0, stream>>>(cvb, resb, scales, out);
}

// Round 22
// 225.154 us; speedup vs baseline: 1.0368x; 1.0368x over previous
//
#include <hip/hip_runtime.h>

// Problem constants
constexpr int B    = 32;
constexpr int CIN  = 64;
constexpr int COUT = 128;
constexpr int T    = 300;
constexpr int V    = 25;
constexpr int TV   = T * V;            // 7500
constexpr long long NPC   = (long long)B * TV;          // 240000 per channel
constexpr long long TOTAL = (long long)B * COUT * TV;   // 30,720,000

typedef short          bf16x8 __attribute__((ext_vector_type(8)));
typedef float          f32x4  __attribute__((ext_vector_type(4)));
typedef unsigned short us8    __attribute__((ext_vector_type(8)));
typedef unsigned short us4    __attribute__((ext_vector_type(4)));

static __device__ __forceinline__ unsigned short f2bf(float f) {
  union { float f; unsigned u; } x; x.f = f;
  unsigned r = x.u + 0x7FFFu + ((x.u >> 16) & 1u);   // RNE
  return (unsigned short)(r >> 16);
}
static __device__ __forceinline__ float bf2f(unsigned short u) {
  union { unsigned u; float f; } x; x.u = ((unsigned)u) << 16;
  return x.f;
}
// HW packed f32->bf16 (RNE): dst = [lo16=cvt(a), hi16=cvt(b)]
static __device__ __forceinline__ unsigned cvtpk(float a, float b) {
  unsigned r;
  asm("v_cvt_pk_bf16_f32 %0, %1, %2" : "=v"(r) : "v"(a), "v"(b));
  return r;
}

// swizzled offsets (verified rounds 4-21)
static __device__ __forceinline__ int xoff(int pos, int c) {      // [pos][c<64]
  return pos * 64 + ((((c >> 3)) ^ (pos & 7)) << 3) + (c & 7);
}
static __device__ __forceinline__ int soff(int c, int pw) {       // [c][pw<128]
  return c * 128 + ((((pw >> 3)) ^ (c & 7)) << 3) + (pw & 7);
}

// ---------------------------------------------------------------------------
// kPrep: all weight/graph-matrix prep in one launch. 696 blocks x 256.
// ---------------------------------------------------------------------------
__global__ __launch_bounds__(256) void kPrep(
    const float* __restrict__ w_t, const float* __restrict__ w_r,
    const float* __restrict__ w_sp, const float* __restrict__ A_hat,
    unsigned short* __restrict__ wb2, unsigned short* __restrict__ wrs2,
    unsigned short* __restrict__ bdt)
{
  int i = blockIdx.x * 256 + threadIdx.x;
  if (i < 147456) {
    int c = i & 127, ok = i >> 7;
    int k = ok % 9, o = ok / 9;
    int idx = ((k * 16 + (c >> 3)) * 128 + o) * 8 + (c & 7);
    wb2[idx] = f2bf(w_t[(o * COUT + c) * 9 + k]);
  } else if (i < 147456 + 16384) {
    int j = i - 147456;
    int c = j & 63, row = j >> 6;
    float v = (row < COUT) ? w_r[row * CIN + c] : w_sp[(row - COUT) * CIN + c];
    wrs2[((c >> 3) * 256 + row) * 8 + (c & 7)] = f2bf(v);
  } else {
    int j = i - 147456 - 16384;
    int pv = j >> 7, pw = j & 127;
    float v = 0.f;
    if (pv < 100 && pw < 100 && (pv / 25) == (pw / 25))
      v = A_hat[(pv % 25) * 25 + (pw % 25)];
    bdt[j] = f2bf(v);
  }
}

// ---------------------------------------------------------------------------
// kA8: spatial front-end, M split across blockIdx.z. (r16-proven base;
// r20: z=1 staging uses float4 loads along pos + us4 LDS packs.)
// grid (75, 32, 2). Measured: VGPR 60, occ 38%, ~92.5 us, no spill.
// ---------------------------------------------------------------------------
__global__ __launch_bounds__(256, 3) void kA8(
    const float* __restrict__ x, const unsigned short* __restrict__ bdt,
    const unsigned short* __restrict__ wrs2,
    unsigned short* __restrict__ resb, unsigned short* __restrict__ h,
    float2* __restrict__ part_rs)
{
  __shared__ unsigned short buf[64 * 128];   // 16KB: xsp(z=0) | xs->axsp(z=1)

  const int tid  = threadIdx.x;
  const int lane = tid & 63;
  const int wave = tid >> 6;
  const int b    = blockIdx.y;
  const int p0   = blockIdx.x * 100;
  const int z    = blockIdx.z;
  const int grp  = lane >> 4;
  const int l15  = lane & 15;

  f32x4 acc[2][7];
#pragma unroll
  for (int m = 0; m < 2; ++m)
#pragma unroll
    for (int n = 0; n < 7; ++n) acc[m][n] = (f32x4)0.f;

  const unsigned short* bsrc = buf;

  if (z == 0) {
    for (int u = tid; u < 16 * 112; u += 256) {
      int pos = u % 112, c4 = u / 112;
      int c0 = c4 * 4;
      float v0 = 0.f, v1 = 0.f, v2 = 0.f, v3 = 0.f;
      if (pos < 100) {
        const float* xp = &x[(b * CIN + c0) * TV + p0 + pos];
        v0 = xp[0]; v1 = xp[TV]; v2 = xp[2 * TV]; v3 = xp[3 * TV];
      }
      uint2 w;
      w.x = cvtpk(v0, v1);
      w.y = cvtpk(v2, v3);
      *(uint2*)&buf[xoff(pos, c0)] = w;
    }
    __syncthreads();
  } else {
    // z=1 staging: unit = (c, pos-quad). One float4 load (lane-contiguous,
    // 16B-aligned) + one us4 LDS pack. pw >= 100 zero-padded.
    for (int u = tid; u < 64 * 32; u += 256) {
      int q = u & 31, c = u >> 5;
      int pos = q * 4;
      float4 v = make_float4(0.f, 0.f, 0.f, 0.f);
      if (pos < 100)
        v = *(const float4*)&x[(b * CIN + c) * TV + p0 + pos];
      us4 pk;
      unsigned u01 = cvtpk(v.x, v.y), u23 = cvtpk(v.z, v.w);
      pk[0] = (unsigned short)u01;
      pk[1] = (unsigned short)(u01 >> 16);
      pk[2] = (unsigned short)u23;
      pk[3] = (unsigned short)(u23 >> 16);
      *(us4*)&buf[soff(c, pos)] = pk;
    }
    __syncthreads();

    bf16x8 xf[4];
#pragma unroll
    for (int ks = 0; ks < 4; ++ks)
      xf[ks] = *(const bf16x8*)&buf[soff(wave * 16 + l15, ks * 32 + grp * 8)];
    __syncthreads();                   // xf in regs; buf reusable as axsp

    {
      f32x4 macc[7];
#pragma unroll
      for (int ni = 0; ni < 7; ++ni) macc[ni] = (f32x4)0.f;
      const int kst[7] = {0, 0, 0, 0, 1, 2, 2};
      const int kcn[7] = {1, 2, 2, 3, 3, 2, 2};
#pragma unroll
      for (int ni = 0; ni < 7; ++ni) {
        for (int kk = 0; kk < kcn[ni]; ++kk) {
          int ks = kst[ni] + kk;
          bf16x8 gf = *(const bf16x8*)&bdt[(ni * 16 + l15) * 128 + ks * 32 + grp * 8];
          macc[ni] = __builtin_amdgcn_mfma_f32_16x16x32_bf16(xf[ks], gf, macc[ni], 0, 0, 0);
        }
      }
      unsigned short* axsp = (unsigned short*)buf;
#pragma unroll
      for (int ni = 0; ni < 7; ++ni) {
#pragma unroll
        for (int r = 0; r < 4; ++r)
          axsp[xoff(ni * 16 + l15, wave * 16 + grp * 4 + r)] = f2bf(macc[ni][r]);
      }
    }
    __syncthreads();                   // axsp ready
  }

  // channel GEMM: 4 waves x 32 rows
#pragma unroll
  for (int ks = 0; ks < 2; ++ks) {
    bf16x8 af[2], bfr[7];
#pragma unroll
    for (int mi = 0; mi < 2; ++mi) {
      int row = z * 128 + wave * 32 + mi * 16 + l15;
      af[mi] = *(const bf16x8*)&wrs2[((ks * 4 + grp) * 256 + row) * 8];
    }
#pragma unroll
    for (int ni = 0; ni < 7; ++ni)
      bfr[ni] = *(const bf16x8*)&bsrc[xoff(ni * 16 + l15, ks * 32 + grp * 8)];
#pragma unroll
    for (int mi = 0; mi < 2; ++mi)
#pragma unroll
      for (int ni = 0; ni < 7; ++ni)
        acc[mi][ni] = __builtin_amdgcn_mfma_f32_16x16x32_bf16(
            af[mi], bfr[ni], acc[mi][ni], 0, 0, 0);
  }

  // epilogue: z=0 resb scalar [b][c][pos]; z=1 h uint2 [b][pos][c]
  if (z == 0) {
#pragma unroll
    for (int mi = 0; mi < 2; ++mi) {
#pragma unroll
      for (int ni = 0; ni < 7; ++ni) {
        int pos = ni * 16 + l15;
        if (pos < 100) {
#pragma unroll
          for (int r = 0; r < 4; ++r) {
            int c = wave * 32 + mi * 16 + grp * 4 + r;
            resb[((long long)(b * COUT + c)) * TV + p0 + pos] = f2bf(acc[mi][ni][r]);
          }
        }
      }
    }
  } else {
#pragma unroll
    for (int mi = 0; mi < 2; ++mi) {
      int o0 = wave * 32 + mi * 16 + grp * 4;
#pragma unroll
      for (int ni = 0; ni < 7; ++ni) {
        int pos = ni * 16 + l15;
        if (pos < 100) {
          uint2 w;
          w.x = cvtpk(acc[mi][ni][0], acc[mi][ni][1]);
          w.y = cvtpk(acc[mi][ni][2], acc[mi][ni][3]);
          *(uint2*)&h[((long long)(b * TV + p0 + pos)) * COUT + o0] = w;
        }
      }
    }
  }

  // fused BN stats: 8-quantity butterfly
  {
    float sv[8], qv[8];
#pragma unroll
    for (int mi = 0; mi < 2; ++mi)
#pragma unroll
      for (int r = 0; r < 4; ++r) {
        float s = 0.f, q = 0.f;
#pragma unroll
        for (int ni = 0; ni < 7; ++ni) {
          float v = (ni < 6 || l15 < 4) ? acc[mi][ni][r] : 0.f;  // pos<100
          s += v; q += v * v;
        }
        sv[mi * 4 + r] = s; qv[mi * 4 + r] = q;
      }
#pragma unroll
    for (int bm = 1; bm < 8; bm <<= 1) {
      const bool up = (l15 & bm) != 0;
#pragma unroll
      for (int i = 0; i < 8; i += 2 * bm) {
        const int j = i + bm;
        float ssend = up ? sv[i] : sv[j];
        float qsend = up ? qv[i] : qv[j];
        float sgot = __shfl_xor(ssend, bm);
        float qgot = __shfl_xor(qsend, bm);
        sv[i] = (up ? sv[j] : sv[i]) + sgot;
        qv[i] = (up ? qv[j] : qv[i]) + qgot;
      }
    }
    sv[0] += __shfl_xor(sv[0], 8);
    qv[0] += __shfl_xor(qv[0], 8);
    if ((l15 & 8) == 0) {
      int slot = ((l15 >> 2) * 16) + grp * 4 + (l15 & 3);
      float2* pw = &part_rs[((((long long)(blockIdx.y * 75 + blockIdx.x)) * 2 + z) * 4 + wave) * 32];
      pw[slot] = make_float2(sv[0], qv[0]);
    }
  }
}

// ---------------------------------------------------------------------------
// kC2v2: finalize res & sp BN from kA8 partials. grid 256.
// ---------------------------------------------------------------------------
__global__ __launch_bounds__(256) void kC2v2(
    const float2* __restrict__ part_rs,
    const float* __restrict__ g_r,  const float* __restrict__ be_r,
    const float* __restrict__ g_sp, const float* __restrict__ be_sp,
    float* __restrict__ scales)
{
  __shared__ float rs[256], rq[256];
  const int row = blockIdx.x;
  const int z = row >> 7, wave = (row >> 5) & 3, slot = row & 31;
  const int tid = threadIdx.x;
  float s = 0.f, q = 0.f;
  for (int bid = tid; bid < 2400; bid += 256) {
    float2 v = part_rs[(((long long)bid * 2 + z) * 4 + wave) * 32 + slot];
    s += v.x; q += v.y;
  }
  rs[tid] = s; rq[tid] = q;
  __syncthreads();
  for (int st = 128; st > 0; st >>= 1) {
    if (tid < st) { rs[tid] += rs[tid + st]; rq[tid] += rq[tid + st]; }
    __syncthreads();
  }
  if (tid == 0) {
    const float n = (float)NPC;
    float m = rs[0] / n, var = rq[0] / n - m * m;
    float iv = rsqrtf(var + 1e-5f);
    if (row < 128) {
      float sc = g_r[row] * iv;
      scales[row] = sc; scales[128 + row] = be_r[row] - m * sc;
    } else {
      int c = row - 128;
      float sc = g_sp[c] * iv;
      scales[256 + c] = sc; scales[384 + c] = be_sp[c] - m * sc;
    }
  }
}

// ---------------------------------------------------------------------------
// kE7d: temporal conv 9x1, implicit MFMA GEMM. NP=256, 512 threads / 8
// waves, single 58KB LDS (r15/r16/r20-proven form: cvt_pk staging,
// compiler-scheduled i+=512 loop). cvb scalar [b][c][pos]; butterfly BN_t
// stats; setprio. grid (30, 32).
// ---------------------------------------------------------------------------
constexpr int NP    = 256;
constexpr int HALO  = 100;               // 4*25
constexpr int STAGE = NP + 2 * HALO;     // 456

__global__ __launch_bounds__(512, 2) void kE7d(
    const unsigned short* __restrict__ h, const unsigned short* __restrict__ wb2,
    const float* __restrict__ scales, unsigned short* __restrict__ cvb,
    float2* __restrict__ part_t)
{
  __shared__ unsigned short hs[STAGE * 64];   // 58368 B
  const int tid  = threadIdx.x;
  const int lane = tid & 63;
  const int wave = tid >> 6;          // 0..7
  const int wm   = wave >> 2, wn = wave & 3;
  const int b    = blockIdx.y;
  const int p0   = blockIdx.x * NP;
  const int grp  = lane >> 4;
  const int l15  = lane & 15;
  const int slot = tid & 7;

  f32x4 acc[4][4];
#pragma unroll
  for (int m = 0; m < 4; ++m)
#pragma unroll
    for (int n = 0; n < 4; ++n) acc[m][n] = (f32x4)0.f;

  for (int cc = 0; cc < 2; ++cc) {
    if (cc) __syncthreads();             // prev chunk's MFMA reads done
    const int c0 = cc * 64;
    float sc[8], sh[8];
#pragma unroll
    for (int e = 0; e < 8; ++e) {
      sc[e] = scales[256 + c0 + slot * 8 + e];
      sh[e] = scales[384 + c0 + slot * 8 + e];
    }
    for (int i = tid; i < STAGE * 8; i += 512) {
      int pos = i >> 3;
      int pg = p0 - HALO + pos;
      uint4 w = {0u, 0u, 0u, 0u};
      if (pg >= 0 && pg < TV) {
        us8 v = *(const us8*)&h[((long long)b * TV + pg) * COUT + c0 + slot * 8];
        float f[8];
#pragma unroll
        for (int e = 0; e < 8; ++e)
          f[e] = fmaxf(bf2f(v[e]) * sc[e] + sh[e], 0.f);
        w.x = cvtpk(f[0], f[1]);
        w.y = cvtpk(f[2], f[3]);
        w.z = cvtpk(f[4], f[5]);
        w.w = cvtpk(f[6], f[7]);
      }
      int si = (pos << 6) + ((slot ^ (pos & 7)) << 3);
      *(uint4*)&hs[si] = w;
    }
    __syncthreads();

    __builtin_amdgcn_s_setprio(1);
    for (int k = 0; k < 9; ++k) {
      const int plb = HALO + wn * 64 + 25 * (k - 4) + l15;
#pragma unroll
      for (int ks = 0; ks < 2; ++ks) {
        bf16x8 af[4], bfr[4];
#pragma unroll
        for (int mi = 0; mi < 4; ++mi) {
          int o = wm * 64 + mi * 16 + l15;
          af[mi] = *(const bf16x8*)&wb2[((k * 16 + cc * 8 + ks * 4 + grp) * 128 + o) * 8];
        }
#pragma unroll
        for (int ni = 0; ni < 4; ++ni) {
          int pl = plb + ni * 16;
          int si = (pl << 6) + (((ks * 4 + grp) ^ (pl & 7)) << 3);
          bfr[ni] = *(const bf16x8*)&hs[si];
        }
#pragma unroll
        for (int mi = 0; mi < 4; ++mi)
#pragma unroll
          for (int ni = 0; ni < 4; ++ni)
            acc[mi][ni] = __builtin_amdgcn_mfma_f32_16x16x32_bf16(
                af[mi], bfr[ni], acc[mi][ni], 0, 0, 0);
      }
    }
    __builtin_amdgcn_s_setprio(0);
  }

  // epilogue: conv -> cvb bf16, [b][c][pos] scalar (plane layout for kH)
#pragma unroll
  for (int mi = 0; mi < 4; ++mi) {
#pragma unroll
    for (int ni = 0; ni < 4; ++ni) {
      int pos = p0 + wn * 64 + ni * 16 + l15;
      if (pos < TV) {
#pragma unroll
        for (int r = 0; r < 4; ++r) {
          int o = wm * 64 + mi * 16 + grp * 4 + r;
          cvb[((long long)(b * COUT + o)) * TV + pos] = f2bf(acc[mi][ni][r]);
        }
      }
    }
  }

  // fused BN_t stats: transpose-butterfly, [bid][wave(8)][64]
  {
    float sv[16], qv[16];
#pragma unroll
    for (int mi = 0; mi < 4; ++mi)
#pragma unroll
      for (int r = 0; r < 4; ++r) {
        float s = 0.f, q = 0.f;
#pragma unroll
        for (int ni = 0; ni < 4; ++ni) {
          int pos = p0 + wn * 64 + ni * 16 + l15;
          float v = (pos < TV) ? acc[mi][ni][r] : 0.f;
          s += v; q += v * v;
        }
        sv[mi * 4 + r] = s; qv[mi * 4 + r] = q;
      }
#pragma unroll
    for (int bm = 1; bm < 16; bm <<= 1) {
      const bool up = (l15 & bm) != 0;
#pragma unroll
      for (int i = 0; i < 16; i += 2 * bm) {
        const int j = i + bm;
        float ssend = up ? sv[i] : sv[j];
        float qsend = up ? qv[i] : qv[j];
        float sgot = __shfl_xor(ssend, bm);
        float qgot = __shfl_xor(qsend, bm);
        sv[i] = (up ? sv[j] : sv[i]) + sgot;
        qv[i] = (up ? qv[j] : qv[i]) + qgot;
      }
    }
    int slt = ((l15 >> 2) * 16) + grp * 4 + (l15 & 3);
    float2* pw = &part_t[(((long long)(blockIdx.y * 30 + blockIdx.x)) * 8 + wave) * 64];
    pw[slt] = make_float2(sv[0], qv[0]);
  }
}

// ---------------------------------------------------------------------------
// kG2: finalize temporal BN from kE7d partials. grid 128. NB=960 blocks.
// ---------------------------------------------------------------------------
__global__ __launch_bounds__(256) void kG2(
    const float2* __restrict__ part_t,
    const float* __restrict__ g_t, const float* __restrict__ be_t,
    float* __restrict__ scales)
{
  __shared__ float rs[256], rq[256];
  const int c = blockIdx.x;
  const int wm = c >> 6, local = c & 63;
  const int tid = threadIdx.x;
  const int NB = 30 * 32;              // 960 blocks
  float s = 0.f, q = 0.f;
  for (int p = tid; p < NB * 4; p += 256) {
    int bid = p >> 2, wn = p & 3;
    float2 v = part_t[((long long)bid * 8 + (wm * 4 + wn)) * 64 + local];
    s += v.x; q += v.y;
  }
  rs[tid] = s; rq[tid] = q;
  __syncthreads();
  for (int st = 128; st > 0; st >>= 1) {
    if (tid < st) { rs[tid] += rs[tid + st]; rq[tid] += rq[tid + st]; }
    __syncthreads();
  }
  if (tid == 0) {
    const float n = (float)NPC;
    float m = rs[0] / n, var = rq[0] / n - m * m;
    float sc = g_t[c] * rsqrtf(var + 1e-5f);
    scales[512 + c] = sc;
    scales[640 + c] = be_t[c] - m * sc;
  }
}

// ---------------------------------------------------------------------------
// kH: out = relu(cvb*sc_t+sh_t + resb*sc_r+sh_r). Plane-based (proven).
// ---------------------------------------------------------------------------
__global__ __launch_bounds__(256) void kH(
    const unsigned short* __restrict__ cvb, const unsigned short* __restrict__ resb,
    const float* __restrict__ scales, float* __restrict__ out)
{
  const int plane = blockIdx.x;          // b*128 + c
  const int c = plane & 127;
  const float sct = scales[512 + c], sht = scales[640 + c];
  const float scr = scales[c],       shr = scales[128 + c];
  const us4* cp = (const us4*)&cvb[(long long)plane * TV];
  const us4* rp = (const us4*)&resb[(long long)plane * TV];
  float* op = &out[(long long)plane * TV];
  for (int u = threadIdx.x; u < 1875; u += 256) {
    us4 o4 = cp[u], r4 = rp[u];
    float4 y;
    y.x = fmaxf(bf2f(o4[0]) * sct + sht + bf2f(r4[0]) * scr + shr, 0.f);
    y.y = fmaxf(bf2f(o4[1]) * sct + sht + bf2f(r4[1]) * scr + shr, 0.f);
    y.z = fmaxf(bf2f(o4[2]) * sct + sht + bf2f(r4[2]) * scr + shr, 0.f);
    y.w = fmaxf(bf2f(o4[3]) * sct + sht + bf2f(r4[3]) * scr + shr, 0.f);
    *(float4*)&op[u * 4] = y;
  }
}

// ---------------------------------------------------------------------------
extern "C" void kernel_launch(void* const* d_in, const int* in_sizes, int n_in,
                              void* d_out, int out_size, void* d_ws, size_t ws_size,
                              hipStream_t stream) {
  const float* x     = (const float*)d_in[0];
  const float* A_hat = (const float*)d_in[1];
  const float* w_sp  = (const float*)d_in[2];
  const float* g_sp  = (const float*)d_in[4];
  const float* be_sp = (const float*)d_in[5];
  const float* w_t   = (const float*)d_in[6];
  const float* g_t   = (const float*)d_in[8];
  const float* be_t  = (const float*)d_in[9];
  const float* w_r   = (const float*)d_in[10];
  const float* g_r   = (const float*)d_in[12];
  const float* be_r  = (const float*)d_in[13];
  float* out = (float*)d_out;

  // workspace carving (shorts)
  unsigned short* base_us = (unsigned short*)d_ws;
  unsigned short* resb = base_us;                          // TOTAL ([b][c][pos])
  unsigned short* h    = base_us + (size_t)TOTAL;          // TOTAL ([b][pos][c])
  unsigned short* cvb  = base_us + (size_t)(2 * TOTAL);    // TOTAL ([b][c][pos])
  unsigned short* wb2  = base_us + (size_t)(3 * TOTAL);    // 147456
  unsigned short* wrs2 = wb2 + 147456;                     // 16384
  unsigned short* bdt  = wrs2 + 16384;                     // 14336
  float2* part_rs = (float2*)(bdt + 14336);                // 2400*2*4*32
  float2* part_t  = part_rs + 2400 * 2 * 4 * 32;           // 960*8*64
  float*  scales  = (float*)(part_t + 960 * 8 * 64);       // 768 floats

  // all prep in one launch
  kPrep<<<696, 256, 0, stream>>>(w_t, w_r, w_sp, A_hat, wb2, wrs2, bdt);
  // spatial front-end (M-split across z, stats fused, float4 z=1 staging)
  kA8<<<dim3(75, 32, 2), 256, 0, stream>>>(x, bdt, wrs2, resb, h, part_rs);
  kC2v2<<<256, 256, 0, stream>>>(part_rs, g_r, be_r, g_sp, be_sp, scales);
  // temporal conv (NP=256, cvt_pk staging, stats fused)
  kE7d<<<dim3(30, 32), 512, 0, stream>>>(h, wb2, scales, cvb, part_t);
  kG2<<<128, 256, 0, stream>>>(part_t, g_t, be_t, scales);
  // fused epilogue (plane-based)
  kH<<<4096, 256, 0, stream>>>(cvb, resb, scales, out);
}